// Round 7
// baseline (891.453 us; speedup 1.0000x reference)
//
#include <hip/hip_runtime.h>
#include <hip/hip_bf16.h>

#define THREADS 256
typedef __hip_bfloat16 bf16;

typedef __bf16 v8bf __attribute__((ext_vector_type(8)));
typedef float  v4f  __attribute__((ext_vector_type(4)));

__device__ __forceinline__ float bfl(unsigned u){ return __uint_as_float(u << 16); }
__device__ __forceinline__ float bfh(unsigned u){ return __uint_as_float(u & 0xffff0000u); }

// ---------------- CSR build (group edges by destination) ----------------
__global__ void hist_k(const int* __restrict__ ei, int* __restrict__ cnt, int E, int ET){
  int i = blockIdx.x*THREADS + threadIdx.x;
  if (i >= ET) return;
  int d = (i < E) ? ei[E + i] : (i - E);   // self-loops appended
  atomicAdd(&cnt[d], 1);
}

__global__ void scan1_k(const int* __restrict__ deg, int* __restrict__ off,
                        int* __restrict__ bsum, int n){
  __shared__ int sh[1024];
  int i = blockIdx.x*1024 + threadIdx.x;
  int v = (i < n) ? deg[i] : 0;
  sh[threadIdx.x] = v;
  __syncthreads();
  for (int s = 1; s < 1024; s <<= 1){
    int t = (threadIdx.x >= s) ? sh[threadIdx.x - s] : 0;
    __syncthreads();
    sh[threadIdx.x] += t;
    __syncthreads();
  }
  if (i < n) off[i+1] = sh[threadIdx.x];
  if (threadIdx.x == 1023) bsum[blockIdx.x] = sh[1023];
}

__global__ void scan2_k(int* __restrict__ bsum, int nb){
  __shared__ int sh[256];
  int v = (threadIdx.x < nb) ? bsum[threadIdx.x] : 0;
  sh[threadIdx.x] = v;
  __syncthreads();
  for (int s = 1; s < 256; s <<= 1){
    int t = (threadIdx.x >= s) ? sh[threadIdx.x - s] : 0;
    __syncthreads();
    sh[threadIdx.x] += t;
    __syncthreads();
  }
  if (threadIdx.x < nb) bsum[threadIdx.x] = sh[threadIdx.x] - v;  // exclusive
}

__global__ void scan3_k(int* __restrict__ off, const int* __restrict__ bsum, int n){
  int i = blockIdx.x*1024 + threadIdx.x;
  if (i < n) off[i+1] += bsum[blockIdx.x];
  if (i == 0) off[0] = 0;
}

__global__ void scatter_k(const int* __restrict__ ei, const int* __restrict__ off,
                          int* __restrict__ cur, int* __restrict__ csr,
                          int* __restrict__ csrd, int E, int ET){
  int i = blockIdx.x*THREADS + threadIdx.x;
  if (i >= ET) return;
  int s, d;
  if (i < E){ s = ei[i]; d = ei[E+i]; } else { s = i - E; d = i - E; }
  int p = off[d] + atomicAdd(&cur[d], 1);
  csr[p] = s;
  csrd[p] = d;
}

// ---------------- dtype prep ----------------
__global__ void convf2b_k(const float4* __restrict__ in, uint2* __restrict__ out, int n4){
  int i = blockIdx.x*THREADS + threadIdx.x;
  if (i >= n4) return;
  float4 v = in[i];
  union { bf16 h[4]; uint2 u; } cv;
  cv.h[0] = __float2bfloat16(v.x); cv.h[1] = __float2bfloat16(v.y);
  cv.h[2] = __float2bfloat16(v.z); cv.h[3] = __float2bfloat16(v.w);
  out[i] = cv.u;
}

// WT[c*K + k] = bf16(W[k*COUT + c])
__global__ void wt_k(const float* __restrict__ W, bf16* __restrict__ WT, int K, int COUT){
  int i = blockIdx.x*THREADS + threadIdx.x;
  if (i >= K*COUT) return;
  int k = i / COUT, c = i - k*COUT;
  WT[(size_t)c*K + k] = __float2bfloat16(W[i]);
}

// extra B-columns for fused alpha: WTX rows COUT..COUT+2 = W_h @ as_h, COUT+3..+5 = W_h @ ad_h
__global__ void va_k(const float* __restrict__ W, const float* __restrict__ as,
                     const float* __restrict__ ad, bf16* __restrict__ WTX,
                     int K, int C, int COUT){
  int i = blockIdx.x*THREADS + threadIdx.x;
  if (i >= 6*K) return;
  int k = i % K, c6 = i / K;
  int h = (c6 < 3) ? c6 : c6 - 3;
  const float* a = ((c6 < 3) ? as : ad) + h*C;
  const float* wp = W + (size_t)k*COUT + h*C;
  float s = 0.f;
  for (int cc = 0; cc < C; cc++) s += wp[cc]*a[cc];
  WTX[(size_t)(COUT + c6)*K + k] = __float2bfloat16(s);
}

// ---------------- MFMA GEMM fused with alpha: C = A@B, aS/aD from extra tile ----
// BT has COUT+16 rows (last tile: cols 0..2 = alpha_src heads, 3..5 = alpha_dst heads;
// cols 6..15 read leftover 0xAA poison = harmless tiny denormals, never stored).
template<int K, int COUT>
__global__ void __launch_bounds__(256) gemm_mfma_k(
    const bf16* __restrict__ A, const bf16* __restrict__ BT,
    bf16* __restrict__ C, float* __restrict__ aS4, float* __restrict__ aD4,
    int nRowTiles)
{
  int wave = threadIdx.x >> 6, lane = threadIdx.x & 63;
  int rt = blockIdx.x*4 + wave;
  if (rt >= nRowTiles) return;
  int half = lane & 15;
  int quad = lane >> 4;
  const __bf16* aBase = (const __bf16*)A + (size_t)(rt*16 + half)*K + quad*8;
  v8bf aF[K/32];
  #pragma unroll
  for (int kk = 0; kk < K/32; kk++) aF[kk] = *(const v8bf*)(aBase + kk*32);
  #pragma unroll
  for (int cb = 0; cb < COUT + 16; cb += 16){
    const __bf16* bBase = (const __bf16*)BT + (size_t)(cb + half)*K + quad*8;
    v4f acc = {0.f, 0.f, 0.f, 0.f};
    #pragma unroll
    for (int kk = 0; kk < K/32; kk++)
      acc = __builtin_amdgcn_mfma_f32_16x16x32_bf16(aF[kk], *(const v8bf*)(bBase + kk*32), acc, 0, 0, 0);
    int orow = rt*16 + quad*4;                 // D: col=lane&15, row=quad*4+reg
    if (cb < COUT){
      bf16* cp = C + (size_t)orow*COUT + cb + half;
      #pragma unroll
      for (int r = 0; r < 4; r++)
        cp[(size_t)r*COUT] = __float2bfloat16(acc[r]);
    } else if (half < 6){
      #pragma unroll
      for (int r = 0; r < 4; r++){
        int row = orow + r;
        if (half < 3) aS4[row*4 + half]     = acc[r];
        else          aD4[row*4 + half - 3] = acc[r];
      }
    }
  }
}

// ---------------- per-edge softmax numerators (edge-parallel, no max shift) ----------------
__global__ void wgt_k(const int* __restrict__ csr, const int* __restrict__ csrd,
                      const float* __restrict__ aS4, const float* __restrict__ aD4,
                      float* __restrict__ wbuf, int ET)
{
  int i = blockIdx.x*THREADS + threadIdx.x;
  if (i >= ET) return;
  int s = csr[i], d = csrd[i];
  const float4 as = *(const float4*)(aS4 + 4*s);
  const float4 ad = *(const float4*)(aD4 + 4*d);
  float x0 = as.x + ad.x; x0 = (x0 > 0.f) ? x0 : 0.2f*x0;
  float x1 = as.y + ad.y; x1 = (x1 > 0.f) ? x1 : 0.2f*x1;
  float x2 = as.z + ad.z; x2 = (x2 > 0.f) ? x2 : 0.2f*x2;
  float4 w = {__expf(x0), __expf(x1), __expf(x2), 0.f};
  *(float4*)(wbuf + 4*i) = w;
}

// ---------------- weighted aggregation (GRP lanes per dst node) ----------------
// Edge loop unrolled x8: 8 independent gathers in flight per lane.
template<int HC, int CSH, int GRP>
__global__ void __launch_bounds__(256) agg_k(
    const int* __restrict__ off, const int* __restrict__ csr,
    const bf16* __restrict__ hbuf, const float* __restrict__ wbuf,
    const float* __restrict__ bias,
    float* __restrict__ outF, bf16* __restrict__ outB,
    int n, int doElu)
{
  constexpr int NPW = 64 / GRP;
  int lane = threadIdx.x & 63;
  int wv = (blockIdx.x*256 + threadIdx.x) >> 6;
  int q = lane % GRP;
  int node = wv*NPW + lane/GRP;
  if (node >= n) return;
  int e0 = off[node], e1 = off[node+1];
  const bool act = q < HC/4;
  const int hq = (4*q) >> CSH;               // head of this lane's 4 channels
  float d0 = 0.f, d1 = 0.f, d2 = 0.f;
  float a0 = 0.f, a1 = 0.f, a2 = 0.f, a3 = 0.f;
  const size_t hoff = 4*q;
  int e = e0;
  for (; e + 8 <= e1; e += 8){
    int s[8]; float4 w[8]; uint2 u[8];
    #pragma unroll
    for (int j = 0; j < 8; j++) s[j] = csr[e+j];
    #pragma unroll
    for (int j = 0; j < 8; j++) w[j] = *(const float4*)(wbuf + 4*(e+j));
    if (act){
      #pragma unroll
      for (int j = 0; j < 8; j++) u[j] = *(const uint2*)(hbuf + (size_t)s[j]*HC + hoff);
    }
    #pragma unroll
    for (int j = 0; j < 8; j++){
      d0 += w[j].x; d1 += w[j].y; d2 += w[j].z;
      if (act){
        float ww = (hq == 0) ? w[j].x : ((hq == 1) ? w[j].y : w[j].z);
        a0 += ww*bfl(u[j].x); a1 += ww*bfh(u[j].x);
        a2 += ww*bfl(u[j].y); a3 += ww*bfh(u[j].y);
      }
    }
  }
  for (; e < e1; e++){
    int s = csr[e];
    const float4 w4 = *(const float4*)(wbuf + 4*e);
    d0 += w4.x; d1 += w4.y; d2 += w4.z;
    if (act){
      uint2 u = *(const uint2*)(hbuf + (size_t)s*HC + hoff);
      float w = (hq == 0) ? w4.x : ((hq == 1) ? w4.y : w4.z);
      a0 += w*bfl(u.x); a1 += w*bfh(u.x); a2 += w*bfl(u.y); a3 += w*bfh(u.y);
    }
  }
  if (act){
    float dh = ((hq == 0) ? d0 : ((hq == 1) ? d1 : d2)) + 1e-16f;
    float inv = 1.f / dh;
    const float4 b = *(const float4*)(bias + 4*q);
    float r0 = a0*inv + b.x, r1 = a1*inv + b.y, r2 = a2*inv + b.z, r3 = a3*inv + b.w;
    if (doElu){
      r0 = (r0 > 0.f) ? r0 : (__expf(r0) - 1.f);
      r1 = (r1 > 0.f) ? r1 : (__expf(r1) - 1.f);
      r2 = (r2 > 0.f) ? r2 : (__expf(r2) - 1.f);
      r3 = (r3 > 0.f) ? r3 : (__expf(r3) - 1.f);
    }
    if (outF){
      float4 o = {r0, r1, r2, r3};
      *(float4*)(outF + (size_t)node*HC + 4*q) = o;
    }
    if (outB){
      union { bf16 h[4]; uint2 u; } cv;
      cv.h[0] = __float2bfloat16(r0); cv.h[1] = __float2bfloat16(r1);
      cv.h[2] = __float2bfloat16(r2); cv.h[3] = __float2bfloat16(r3);
      *(uint2*)(outB + (size_t)node*HC + 4*q) = cv.u;
    }
  }
}

// ---------------- graph boundaries via binary search on sorted batch ----------------
__global__ void gboff_k(const int* __restrict__ batch, int* __restrict__ goff, int n, int G){
  int g = blockIdx.x*THREADS + threadIdx.x;
  if (g > G) return;
  if (g == G){ goff[G] = n; return; }
  int lo = 0, hi = n;
  while (lo < hi){ int mid = (lo + hi) >> 1; if (batch[mid] < g) lo = mid + 1; else hi = mid; }
  goff[g] = lo;
}

// ---------------- fused mean-pool + relu + linear + sigmoid + BCE (wave per graph) ---
__global__ void __launch_bounds__(256) pool_logits_k(
    const float* __restrict__ h3, const int* __restrict__ goff,
    const float* __restrict__ Wl, const float* __restrict__ bl,
    const float* __restrict__ y, float* __restrict__ outp,
    float* __restrict__ lossAcc, int G)
{
  int lane = threadIdx.x & 63;
  int g = (blockIdx.x*256 + threadIdx.x) >> 6;
  if (g >= G) return;
  int n0 = goff[g], n1 = goff[g+1];
  int cnt = n1 - n0;
  float acc = 0.f, acc2 = 0.f, wl = 0.f;
  if (lane < 48){
    wl = Wl[lane];
    const float* p = h3 + (size_t)n0*48 + lane;
    int i = 0;
    for (; i + 2 <= cnt; i += 2){ acc += p[(size_t)i*48]; acc2 += p[(size_t)(i+1)*48]; }
    if (i < cnt) acc += p[(size_t)i*48];
    acc += acc2;
  }
  float inv = 1.f / fmaxf((float)cnt, 1.f);
  float v = fmaxf(acc*inv, 0.f) * wl;
  for (int o = 32; o > 0; o >>= 1) v += __shfl_down(v, o);
  if (lane == 0){
    float logit = v + bl[0];
    outp[g] = 1.f / (1.f + __expf(-logit));
    float t = y[g];
    float sp = (logit > 0.f) ? (logit + log1pf(__expf(-logit))) : log1pf(__expf(logit));
    atomicAdd(lossAcc, sp - t*logit);
  }
}

__global__ void fin_k(const float* __restrict__ lossAcc, float* __restrict__ outp, int gtot){
  outp[gtot] = lossAcc[0] / (float)gtot;
}

// ---------------- launch ----------------
extern "C" void kernel_launch(void* const* d_in, const int* in_sizes, int n_in,
                              void* d_out, int out_size, void* d_ws, size_t ws_size,
                              hipStream_t stream)
{
  (void)n_in; (void)out_size; (void)ws_size;
  const float* x    = (const float*)d_in[0];
  const float* y    = (const float*)d_in[1];
  const int*  ei    = (const int*)d_in[2];
  const int*  batch = (const int*)d_in[3];
  const float* W1 = (const float*)d_in[4];
  const float* as1= (const float*)d_in[5];
  const float* ad1= (const float*)d_in[6];
  const float* b1 = (const float*)d_in[7];
  const float* W2 = (const float*)d_in[8];
  const float* as2= (const float*)d_in[9];
  const float* ad2= (const float*)d_in[10];
  const float* b2 = (const float*)d_in[11];
  const float* W3 = (const float*)d_in[12];
  const float* as3= (const float*)d_in[13];
  const float* ad3= (const float*)d_in[14];
  const float* b3 = (const float*)d_in[15];
  const float* Wl = (const float*)d_in[16];
  const float* bl = (const float*)d_in[17];
  float* outp = (float*)d_out;

  int Nn = in_sizes[0] / 128;   // 100000 (multiple of 16)
  int Gg = in_sizes[1];
  int Ee = in_sizes[2] / 2;
  int ET = Ee + Nn;

  char* p = (char*)d_ws;
  auto carve = [&](size_t bytes) -> void* {
    void* r = (void*)p; p += (bytes + 255) & ~(size_t)255; return r;
  };
  int*   off     = (int*)  carve((size_t)(Nn+1)*4);
  int*   cnt     = (int*)  carve((size_t)Nn*4);
  int*   csr     = (int*)  carve((size_t)ET*4);
  int*   csrd    = (int*)  carve((size_t)ET*4);
  float* wbuf    = (float*)carve((size_t)ET*4*4);
  int*   bsum    = (int*)  carve(256*4);
  float* aS4     = (float*)carve((size_t)Nn*4*4);
  float* aD4     = (float*)carve((size_t)Nn*4*4);
  int*   goff    = (int*)  carve((size_t)(Gg+1)*4);
  float* lossAcc = (float*)carve(4);
  bf16*  WT1     = (bf16*) carve((size_t)(192+16)*128*2);
  bf16*  WT2     = (bf16*) carve((size_t)(96+16)*192*2);
  bf16*  WT3     = (bf16*) carve((size_t)(48+16)*96*2);
  bf16*  bufH    = (bf16*) carve((size_t)Nn*192*2);   // GEMM out (h), agg in
  bf16*  bufA    = (bf16*) carve((size_t)Nn*192*2);   // GEMM A-operand
  // layer-3 f32 out for pooling: alias into the unused tail of bufH's region
  float* bufO    = (float*)((char*)bufH + ((size_t)Nn*96 + 255 & ~(size_t)255));

  int NB = (Nn + 1023) / 1024;
  int ebk = (ET + THREADS - 1) / THREADS;

  // CSR by destination
  hipMemsetAsync(cnt, 0, (size_t)Nn*4, stream);
  hist_k<<<ebk, THREADS, 0, stream>>>(ei, cnt, Ee, ET);
  scan1_k<<<NB, 1024, 0, stream>>>(cnt, off, bsum, Nn);
  scan2_k<<<1, 256, 0, stream>>>(bsum, NB);
  scan3_k<<<NB, 1024, 0, stream>>>(off, bsum, Nn);
  hipMemsetAsync(cnt, 0, (size_t)Nn*4, stream);
  scatter_k<<<ebk, THREADS, 0, stream>>>(ei, off, cnt, csr, csrd, Ee, ET);

  // dtype prep + fused-alpha B-columns + graph boundaries
  convf2b_k<<<(Nn*32 + THREADS-1)/THREADS, THREADS, 0, stream>>>((const float4*)x, (uint2*)bufA, Nn*32);
  wt_k<<<(128*192 + THREADS-1)/THREADS, THREADS, 0, stream>>>(W1, WT1, 128, 192);
  wt_k<<<(192*96  + THREADS-1)/THREADS, THREADS, 0, stream>>>(W2, WT2, 192, 96);
  wt_k<<<(96*48   + THREADS-1)/THREADS, THREADS, 0, stream>>>(W3, WT3, 96, 48);
  va_k<<<(6*128 + THREADS-1)/THREADS, THREADS, 0, stream>>>(W1, as1, ad1, WT1, 128, 64, 192);
  va_k<<<(6*192 + THREADS-1)/THREADS, THREADS, 0, stream>>>(W2, as2, ad2, WT2, 192, 32, 96);
  va_k<<<(6*96  + THREADS-1)/THREADS, THREADS, 0, stream>>>(W3, as3, ad3, WT3, 96, 16, 48);
  gboff_k<<<(Gg + 1 + THREADS-1)/THREADS, THREADS, 0, stream>>>(batch, goff, Nn, Gg);

  int nRT = Nn / 16;                 // 6250 row tiles
  int gx  = (nRT + 3) / 4;           // 4 waves/block
  int gb1 = (Nn + 3) / 4;            // GRP=64: 1 node/wave
  int gb2 = (Nn + 7) / 8;            // GRP=32: 2 nodes/wave
  int gb3 = (Nn + 15) / 16;          // GRP=16: 4 nodes/wave

  // layer 1: 128 -> 3x64
  gemm_mfma_k<128,192><<<gx, 256, 0, stream>>>(bufA, WT1, bufH, aS4, aD4, nRT);
  wgt_k<<<ebk, THREADS, 0, stream>>>(csr, csrd, aS4, aD4, wbuf, ET);
  agg_k<192,6,64><<<gb1, 256, 0, stream>>>(off, csr, bufH, wbuf, b1, nullptr, bufA, Nn, 1);
  // layer 2: 192 -> 3x32
  gemm_mfma_k<192,96><<<gx, 256, 0, stream>>>(bufA, WT2, bufH, aS4, aD4, nRT);
  wgt_k<<<ebk, THREADS, 0, stream>>>(csr, csrd, aS4, aD4, wbuf, ET);
  agg_k<96,5,32><<<gb2, 256, 0, stream>>>(off, csr, bufH, wbuf, b2, nullptr, bufA, Nn, 1);
  // layer 3: 96 -> 3x16 (no ELU)
  gemm_mfma_k<96,48><<<gx, 256, 0, stream>>>(bufA, WT3, bufH, aS4, aD4, nRT);
  wgt_k<<<ebk, THREADS, 0, stream>>>(csr, csrd, aS4, aD4, wbuf, ET);
  agg_k<48,4,16><<<gb3, 256, 0, stream>>>(off, csr, bufH, wbuf, b3, bufO, nullptr, Nn, 0);

  // fused mean pool + relu + linear + sigmoid + BCE loss
  hipMemsetAsync(lossAcc, 0, 4, stream);
  pool_logits_k<<<(Gg + 3)/4, 256, 0, stream>>>(bufO, goff, Wl, bl, y, outp, lossAcc, Gg);
  fin_k<<<1, 1, 0, stream>>>(lossAcc, outp, Gg);
}

// Round 8
// 812.920 us; speedup vs baseline: 1.0966x; 1.0966x over previous
//
#include <hip/hip_runtime.h>
#include <hip/hip_bf16.h>

#define THREADS 256
typedef __hip_bfloat16 bf16;

typedef __bf16 v8bf __attribute__((ext_vector_type(8)));
typedef float  v4f  __attribute__((ext_vector_type(4)));

__device__ __forceinline__ float bfl(unsigned u){ return __uint_as_float(u << 16); }
__device__ __forceinline__ float bfh(unsigned u){ return __uint_as_float(u & 0xffff0000u); }

// ---------------- CSR build (group edges by destination) ----------------
__global__ void hist_k(const int* __restrict__ ei, int* __restrict__ cnt, int E, int ET){
  int i = blockIdx.x*THREADS + threadIdx.x;
  if (i >= ET) return;
  int d = (i < E) ? ei[E + i] : (i - E);   // self-loops appended
  atomicAdd(&cnt[d], 1);
}

__global__ void scan1_k(const int* __restrict__ deg, int* __restrict__ off,
                        int* __restrict__ bsum, int n){
  __shared__ int sh[1024];
  int i = blockIdx.x*1024 + threadIdx.x;
  int v = (i < n) ? deg[i] : 0;
  sh[threadIdx.x] = v;
  __syncthreads();
  for (int s = 1; s < 1024; s <<= 1){
    int t = (threadIdx.x >= s) ? sh[threadIdx.x - s] : 0;
    __syncthreads();
    sh[threadIdx.x] += t;
    __syncthreads();
  }
  if (i < n) off[i+1] = sh[threadIdx.x];
  if (threadIdx.x == 1023) bsum[blockIdx.x] = sh[1023];
}

__global__ void scan2_k(int* __restrict__ bsum, int nb){
  __shared__ int sh[256];
  int v = (threadIdx.x < nb) ? bsum[threadIdx.x] : 0;
  sh[threadIdx.x] = v;
  __syncthreads();
  for (int s = 1; s < 256; s <<= 1){
    int t = (threadIdx.x >= s) ? sh[threadIdx.x - s] : 0;
    __syncthreads();
    sh[threadIdx.x] += t;
    __syncthreads();
  }
  if (threadIdx.x < nb) bsum[threadIdx.x] = sh[threadIdx.x] - v;  // exclusive
}

__global__ void scan3_k(int* __restrict__ off, const int* __restrict__ bsum, int n){
  int i = blockIdx.x*1024 + threadIdx.x;
  if (i < n) off[i+1] += bsum[blockIdx.x];
  if (i == 0) off[0] = 0;
}

__global__ void scatter_k(const int* __restrict__ ei, const int* __restrict__ off,
                          int* __restrict__ cur, int* __restrict__ csr,
                          int* __restrict__ csrd, int E, int ET){
  int i = blockIdx.x*THREADS + threadIdx.x;
  if (i >= ET) return;
  int s, d;
  if (i < E){ s = ei[i]; d = ei[E+i]; } else { s = i - E; d = i - E; }
  int p = off[d] + atomicAdd(&cur[d], 1);
  csr[p] = s;
  csrd[p] = d;
}

// ---------------- dtype prep ----------------
__global__ void convf2b_k(const float4* __restrict__ in, uint2* __restrict__ out, int n4){
  int i = blockIdx.x*THREADS + threadIdx.x;
  if (i >= n4) return;
  float4 v = in[i];
  union { bf16 h[4]; uint2 u; } cv;
  cv.h[0] = __float2bfloat16(v.x); cv.h[1] = __float2bfloat16(v.y);
  cv.h[2] = __float2bfloat16(v.z); cv.h[3] = __float2bfloat16(v.w);
  out[i] = cv.u;
}

// WT[c*K + k] = bf16(W[k*COUT + c])
__global__ void wt_k(const float* __restrict__ W, bf16* __restrict__ WT, int K, int COUT){
  int i = blockIdx.x*THREADS + threadIdx.x;
  if (i >= K*COUT) return;
  int k = i / COUT, c = i - k*COUT;
  WT[(size_t)c*K + k] = __float2bfloat16(W[i]);
}

// extra B-columns for fused alpha: WTX rows COUT..COUT+2 = W_h @ as_h, COUT+3..+5 = W_h @ ad_h
__global__ void va_k(const float* __restrict__ W, const float* __restrict__ as,
                     const float* __restrict__ ad, bf16* __restrict__ WTX,
                     int K, int C, int COUT){
  int i = blockIdx.x*THREADS + threadIdx.x;
  if (i >= 6*K) return;
  int k = i % K, c6 = i / K;
  int h = (c6 < 3) ? c6 : c6 - 3;
  const float* a = ((c6 < 3) ? as : ad) + h*C;
  const float* wp = W + (size_t)k*COUT + h*C;
  float s = 0.f;
  for (int cc = 0; cc < C; cc++) s += wp[cc]*a[cc];
  WTX[(size_t)(COUT + c6)*K + k] = __float2bfloat16(s);
}

// ---------------- MFMA GEMM fused with alpha: C = A@B, aS/aD from extra tile ----
template<int K, int COUT>
__global__ void __launch_bounds__(256) gemm_mfma_k(
    const bf16* __restrict__ A, const bf16* __restrict__ BT,
    bf16* __restrict__ C, float* __restrict__ aS4, float* __restrict__ aD4,
    int nRowTiles)
{
  int wave = threadIdx.x >> 6, lane = threadIdx.x & 63;
  int rt = blockIdx.x*4 + wave;
  if (rt >= nRowTiles) return;
  int half = lane & 15;
  int quad = lane >> 4;
  const __bf16* aBase = (const __bf16*)A + (size_t)(rt*16 + half)*K + quad*8;
  v8bf aF[K/32];
  #pragma unroll
  for (int kk = 0; kk < K/32; kk++) aF[kk] = *(const v8bf*)(aBase + kk*32);
  #pragma unroll
  for (int cb = 0; cb < COUT + 16; cb += 16){
    const __bf16* bBase = (const __bf16*)BT + (size_t)(cb + half)*K + quad*8;
    v4f acc = {0.f, 0.f, 0.f, 0.f};
    #pragma unroll
    for (int kk = 0; kk < K/32; kk++)
      acc = __builtin_amdgcn_mfma_f32_16x16x32_bf16(aF[kk], *(const v8bf*)(bBase + kk*32), acc, 0, 0, 0);
    int orow = rt*16 + quad*4;                 // D: col=lane&15, row=quad*4+reg
    if (cb < COUT){
      bf16* cp = C + (size_t)orow*COUT + cb + half;
      #pragma unroll
      for (int r = 0; r < 4; r++)
        cp[(size_t)r*COUT] = __float2bfloat16(acc[r]);
    } else if (half < 6){
      #pragma unroll
      for (int r = 0; r < 4; r++){
        int row = orow + r;
        if (half < 3) aS4[row*4 + half]     = acc[r];
        else          aD4[row*4 + half - 3] = acc[r];
      }
    }
  }
}

// ---------------- per-edge softmax numerators (edge-parallel, no max shift) ----------------
__global__ void wgt_k(const int* __restrict__ csr, const int* __restrict__ csrd,
                      const float* __restrict__ aS4, const float* __restrict__ aD4,
                      float* __restrict__ wbuf, int ET)
{
  int i = blockIdx.x*THREADS + threadIdx.x;
  if (i >= ET) return;
  int s = csr[i], d = csrd[i];
  const float4 as = *(const float4*)(aS4 + 4*s);
  const float4 ad = *(const float4*)(aD4 + 4*d);
  float x0 = as.x + ad.x; x0 = (x0 > 0.f) ? x0 : 0.2f*x0;
  float x1 = as.y + ad.y; x1 = (x1 > 0.f) ? x1 : 0.2f*x1;
  float x2 = as.z + ad.z; x2 = (x2 > 0.f) ? x2 : 0.2f*x2;
  float4 w = {__expf(x0), __expf(x1), __expf(x2), 0.f};
  *(float4*)(wbuf + 4*i) = w;
}

// ---------------- weighted aggregation (GRP lanes per dst node) ----------------
// Edge loop unrolled x4 with explicit scalars (proven 32-VGPR / 8-wave form).
template<int HC, int CSH, int GRP>
__global__ void __launch_bounds__(256) agg_k(
    const int* __restrict__ off, const int* __restrict__ csr,
    const bf16* __restrict__ hbuf, const float* __restrict__ wbuf,
    const float* __restrict__ bias,
    float* __restrict__ outF, bf16* __restrict__ outB,
    int n, int doElu)
{
  constexpr int NPW = 64 / GRP;
  int lane = threadIdx.x & 63;
  int wv = (blockIdx.x*256 + threadIdx.x) >> 6;
  int q = lane % GRP;
  int node = wv*NPW + lane/GRP;
  if (node >= n) return;
  int e0 = off[node], e1 = off[node+1];
  const bool act = q < HC/4;
  const int hq = (4*q) >> CSH;               // head of this lane's 4 channels
  float d0 = 0.f, d1 = 0.f, d2 = 0.f;
  float a0 = 0.f, a1 = 0.f, a2 = 0.f, a3 = 0.f;
  const size_t hoff = 4*q;
  int e = e0;
  for (; e + 4 <= e1; e += 4){
    int s0 = csr[e+0], s1 = csr[e+1], s2 = csr[e+2], s3 = csr[e+3];
    float4 wA = *(const float4*)(wbuf + 4*(e+0));
    float4 wB = *(const float4*)(wbuf + 4*(e+1));
    float4 wC = *(const float4*)(wbuf + 4*(e+2));
    float4 wD = *(const float4*)(wbuf + 4*(e+3));
    d0 += wA.x + wB.x + wC.x + wD.x;
    d1 += wA.y + wB.y + wC.y + wD.y;
    d2 += wA.z + wB.z + wC.z + wD.z;
    if (act){
      uint2 u0 = *(const uint2*)(hbuf + (size_t)s0*HC + hoff);
      uint2 u1 = *(const uint2*)(hbuf + (size_t)s1*HC + hoff);
      uint2 u2 = *(const uint2*)(hbuf + (size_t)s2*HC + hoff);
      uint2 u3 = *(const uint2*)(hbuf + (size_t)s3*HC + hoff);
      float w0 = (hq == 0) ? wA.x : ((hq == 1) ? wA.y : wA.z);
      float w1 = (hq == 0) ? wB.x : ((hq == 1) ? wB.y : wB.z);
      float w2 = (hq == 0) ? wC.x : ((hq == 1) ? wC.y : wC.z);
      float w3 = (hq == 0) ? wD.x : ((hq == 1) ? wD.y : wD.z);
      a0 += w0*bfl(u0.x); a1 += w0*bfh(u0.x); a2 += w0*bfl(u0.y); a3 += w0*bfh(u0.y);
      a0 += w1*bfl(u1.x); a1 += w1*bfh(u1.x); a2 += w1*bfl(u1.y); a3 += w1*bfh(u1.y);
      a0 += w2*bfl(u2.x); a1 += w2*bfh(u2.x); a2 += w2*bfl(u2.y); a3 += w2*bfh(u2.y);
      a0 += w3*bfl(u3.x); a1 += w3*bfh(u3.x); a2 += w3*bfl(u3.y); a3 += w3*bfh(u3.y);
    }
  }
  for (; e < e1; e++){
    int s = csr[e];
    const float4 w4 = *(const float4*)(wbuf + 4*e);
    d0 += w4.x; d1 += w4.y; d2 += w4.z;
    if (act){
      uint2 u = *(const uint2*)(hbuf + (size_t)s*HC + hoff);
      float w = (hq == 0) ? w4.x : ((hq == 1) ? w4.y : w4.z);
      a0 += w*bfl(u.x); a1 += w*bfh(u.x); a2 += w*bfl(u.y); a3 += w*bfh(u.y);
    }
  }
  if (act){
    float dh = ((hq == 0) ? d0 : ((hq == 1) ? d1 : d2)) + 1e-16f;
    float inv = 1.f / dh;
    const float4 b = *(const float4*)(bias + 4*q);
    float r0 = a0*inv + b.x, r1 = a1*inv + b.y, r2 = a2*inv + b.z, r3 = a3*inv + b.w;
    if (doElu){
      r0 = (r0 > 0.f) ? r0 : (__expf(r0) - 1.f);
      r1 = (r1 > 0.f) ? r1 : (__expf(r1) - 1.f);
      r2 = (r2 > 0.f) ? r2 : (__expf(r2) - 1.f);
      r3 = (r3 > 0.f) ? r3 : (__expf(r3) - 1.f);
    }
    if (outF){
      float4 o = {r0, r1, r2, r3};
      *(float4*)(outF + (size_t)node*HC + 4*q) = o;
    }
    if (outB){
      union { bf16 h[4]; uint2 u; } cv;
      cv.h[0] = __float2bfloat16(r0); cv.h[1] = __float2bfloat16(r1);
      cv.h[2] = __float2bfloat16(r2); cv.h[3] = __float2bfloat16(r3);
      *(uint2*)(outB + (size_t)node*HC + 4*q) = cv.u;
    }
  }
}

// ---------------- graph boundaries via binary search on sorted batch ----------------
__global__ void gboff_k(const int* __restrict__ batch, int* __restrict__ goff, int n, int G){
  int g = blockIdx.x*THREADS + threadIdx.x;
  if (g > G) return;
  if (g == G){ goff[G] = n; return; }
  int lo = 0, hi = n;
  while (lo < hi){ int mid = (lo + hi) >> 1; if (batch[mid] < g) lo = mid + 1; else hi = mid; }
  goff[g] = lo;
}

// ---------------- fused mean-pool + relu + linear + sigmoid + BCE (wave per graph) ---
__global__ void __launch_bounds__(256) pool_logits_k(
    const float* __restrict__ h3, const int* __restrict__ goff,
    const float* __restrict__ Wl, const float* __restrict__ bl,
    const float* __restrict__ y, float* __restrict__ outp,
    float* __restrict__ lossAcc, int G)
{
  int lane = threadIdx.x & 63;
  int g = (blockIdx.x*256 + threadIdx.x) >> 6;
  if (g >= G) return;
  int n0 = goff[g], n1 = goff[g+1];
  int cnt = n1 - n0;
  float acc = 0.f, acc2 = 0.f, wl = 0.f;
  if (lane < 48){
    wl = Wl[lane];
    const float* p = h3 + (size_t)n0*48 + lane;
    int i = 0;
    for (; i + 2 <= cnt; i += 2){ acc += p[(size_t)i*48]; acc2 += p[(size_t)(i+1)*48]; }
    if (i < cnt) acc += p[(size_t)i*48];
    acc += acc2;
  }
  float inv = 1.f / fmaxf((float)cnt, 1.f);
  float v = fmaxf(acc*inv, 0.f) * wl;
  for (int o = 32; o > 0; o >>= 1) v += __shfl_down(v, o);
  if (lane == 0){
    float logit = v + bl[0];
    outp[g] = 1.f / (1.f + __expf(-logit));
    float t = y[g];
    float sp = (logit > 0.f) ? (logit + log1pf(__expf(-logit))) : log1pf(__expf(logit));
    atomicAdd(lossAcc, sp - t*logit);
  }
}

__global__ void fin_k(const float* __restrict__ lossAcc, float* __restrict__ outp, int gtot){
  outp[gtot] = lossAcc[0] / (float)gtot;
}

// ---------------- launch ----------------
extern "C" void kernel_launch(void* const* d_in, const int* in_sizes, int n_in,
                              void* d_out, int out_size, void* d_ws, size_t ws_size,
                              hipStream_t stream)
{
  (void)n_in; (void)out_size; (void)ws_size;
  const float* x    = (const float*)d_in[0];
  const float* y    = (const float*)d_in[1];
  const int*  ei    = (const int*)d_in[2];
  const int*  batch = (const int*)d_in[3];
  const float* W1 = (const float*)d_in[4];
  const float* as1= (const float*)d_in[5];
  const float* ad1= (const float*)d_in[6];
  const float* b1 = (const float*)d_in[7];
  const float* W2 = (const float*)d_in[8];
  const float* as2= (const float*)d_in[9];
  const float* ad2= (const float*)d_in[10];
  const float* b2 = (const float*)d_in[11];
  const float* W3 = (const float*)d_in[12];
  const float* as3= (const float*)d_in[13];
  const float* ad3= (const float*)d_in[14];
  const float* b3 = (const float*)d_in[15];
  const float* Wl = (const float*)d_in[16];
  const float* bl = (const float*)d_in[17];
  float* outp = (float*)d_out;

  int Nn = in_sizes[0] / 128;   // 100000 (multiple of 16)
  int Gg = in_sizes[1];
  int Ee = in_sizes[2] / 2;
  int ET = Ee + Nn;

  char* p = (char*)d_ws;
  auto carve = [&](size_t bytes) -> void* {
    void* r = (void*)p; p += (bytes + 255) & ~(size_t)255; return r;
  };
  int*   off     = (int*)  carve((size_t)(Nn+1)*4);
  int*   cnt     = (int*)  carve((size_t)Nn*4);
  int*   csr     = (int*)  carve((size_t)ET*4);
  int*   csrd    = (int*)  carve((size_t)ET*4);
  float* wbuf    = (float*)carve((size_t)ET*4*4);
  int*   bsum    = (int*)  carve(256*4);
  float* aS4     = (float*)carve((size_t)Nn*4*4);
  float* aD4     = (float*)carve((size_t)Nn*4*4);
  int*   goff    = (int*)  carve((size_t)(Gg+1)*4);
  float* lossAcc = (float*)carve(4);
  bf16*  WT1     = (bf16*) carve((size_t)(192+16)*128*2);
  bf16*  WT2     = (bf16*) carve((size_t)(96+16)*192*2);
  bf16*  WT3     = (bf16*) carve((size_t)(48+16)*96*2);
  bf16*  bufH    = (bf16*) carve((size_t)Nn*192*2);   // GEMM out (h), agg in
  bf16*  bufA    = (bf16*) carve((size_t)Nn*192*2);   // GEMM A-operand
  // layer-3 f32 out for pooling: alias into the unused tail of bufH's region
  float* bufO    = (float*)((char*)bufH + ((size_t)Nn*96 + 255 & ~(size_t)255));

  int NB = (Nn + 1023) / 1024;
  int ebk = (ET + THREADS - 1) / THREADS;

  // CSR by destination
  hipMemsetAsync(cnt, 0, (size_t)Nn*4, stream);
  hist_k<<<ebk, THREADS, 0, stream>>>(ei, cnt, Ee, ET);
  scan1_k<<<NB, 1024, 0, stream>>>(cnt, off, bsum, Nn);
  scan2_k<<<1, 256, 0, stream>>>(bsum, NB);
  scan3_k<<<NB, 1024, 0, stream>>>(off, bsum, Nn);
  hipMemsetAsync(cnt, 0, (size_t)Nn*4, stream);
  scatter_k<<<ebk, THREADS, 0, stream>>>(ei, off, cnt, csr, csrd, Ee, ET);

  // dtype prep + fused-alpha B-columns + graph boundaries
  convf2b_k<<<(Nn*32 + THREADS-1)/THREADS, THREADS, 0, stream>>>((const float4*)x, (uint2*)bufA, Nn*32);
  wt_k<<<(128*192 + THREADS-1)/THREADS, THREADS, 0, stream>>>(W1, WT1, 128, 192);
  wt_k<<<(192*96  + THREADS-1)/THREADS, THREADS, 0, stream>>>(W2, WT2, 192, 96);
  wt_k<<<(96*48   + THREADS-1)/THREADS, THREADS, 0, stream>>>(W3, WT3, 96, 48);
  va_k<<<(6*128 + THREADS-1)/THREADS, THREADS, 0, stream>>>(W1, as1, ad1, WT1, 128, 64, 192);
  va_k<<<(6*192 + THREADS-1)/THREADS, THREADS, 0, stream>>>(W2, as2, ad2, WT2, 192, 32, 96);
  va_k<<<(6*96  + THREADS-1)/THREADS, THREADS, 0, stream>>>(W3, as3, ad3, WT3, 96, 16, 48);
  gboff_k<<<(Gg + 1 + THREADS-1)/THREADS, THREADS, 0, stream>>>(batch, goff, Nn, Gg);

  int nRT = Nn / 16;                 // 6250 row tiles
  int gx  = (nRT + 3) / 4;           // 4 waves/block
  int gb1 = (Nn + 3) / 4;            // GRP=64: 1 node/wave
  int gb2 = (Nn + 7) / 8;            // GRP=32: 2 nodes/wave
  int gb3 = (Nn + 15) / 16;          // GRP=16: 4 nodes/wave

  // layer 1: 128 -> 3x64
  gemm_mfma_k<128,192><<<gx, 256, 0, stream>>>(bufA, WT1, bufH, aS4, aD4, nRT);
  wgt_k<<<ebk, THREADS, 0, stream>>>(csr, csrd, aS4, aD4, wbuf, ET);
  agg_k<192,6,64><<<gb1, 256, 0, stream>>>(off, csr, bufH, wbuf, b1, nullptr, bufA, Nn, 1);
  // layer 2: 192 -> 3x32
  gemm_mfma_k<192,96><<<gx, 256, 0, stream>>>(bufA, WT2, bufH, aS4, aD4, nRT);
  wgt_k<<<ebk, THREADS, 0, stream>>>(csr, csrd, aS4, aD4, wbuf, ET);
  agg_k<96,5,32><<<gb2, 256, 0, stream>>>(off, csr, bufH, wbuf, b2, nullptr, bufA, Nn, 1);
  // layer 3: 96 -> 3x16 (no ELU)
  gemm_mfma_k<96,48><<<gx, 256, 0, stream>>>(bufA, WT3, bufH, aS4, aD4, nRT);
  wgt_k<<<ebk, THREADS, 0, stream>>>(csr, csrd, aS4, aD4, wbuf, ET);
  agg_k<48,4,16><<<gb3, 256, 0, stream>>>(off, csr, bufH, wbuf, b3, bufO, nullptr, Nn, 0);

  // fused mean pool + relu + linear + sigmoid + BCE loss
  hipMemsetAsync(lossAcc, 0, 4, stream);
  pool_logits_k<<<(Gg + 3)/4, 256, 0, stream>>>(bufO, goff, Wl, bl, y, outp, lossAcc, Gg);
  fin_k<<<1, 1, 0, stream>>>(lossAcc, outp, Gg);
}